// Round 1
// baseline (785.406 us; speedup 1.0000x reference)
//
#include <hip/hip_runtime.h>
#include <hip/hip_bf16.h>

#define NB 2
#define ND 8
#define NHH 56
#define NWW 56
#define NC 128
#define NHEAD 4
#define DHEAD 32
#define NSEQ 392            // 8*7*7
#define NWIN 128            // 2*8*8
#define NTOK (NB*ND*NHH*NWW) // 50176
#define NHID 512
#define EPSV 1e-5f

typedef unsigned int uint32;

// windowed token index -> source spatial token index
// win = b*64 + gh*8 + gw ; n = d*49 + p*7 + q ; (h,w) = (p*8+gh, q*8+gw)
__device__ __forceinline__ int win_to_src(int grow) {
  int win = grow / NSEQ, n = grow % NSEQ;
  int b = win >> 6, gh = (win >> 3) & 7, gw = win & 7;
  int d = n / 49, rem = n % 49;
  int p = rem / 7, q = rem % 7;
  int h = p * 8 + gh, w = q * 8 + gw;
  return ((b * ND + d) * NHH + h) * NWW + w;
}

// ---------------- LayerNorm (one block = one token row of 128) ----------------
__global__ void k_ln(const float* __restrict__ xin, const float* __restrict__ g,
                     const float* __restrict__ bsh, float* __restrict__ out) {
  int t = blockIdx.x, o = threadIdx.x;
  __shared__ float s1[128], s2[128];
  float v = xin[(long)t * NC + o];
  s1[o] = v; s2[o] = v * v;
  __syncthreads();
  for (int off = 64; off > 0; off >>= 1) {
    if (o < off) { s1[o] += s1[o + off]; s2[o] += s2[o + off]; }
    __syncthreads();
  }
  float mu = s1[0] * (1.0f / NC);
  float var = s2[0] * (1.0f / NC) - mu * mu;
  float r = rsqrtf(var + EPSV);
  out[(long)t * NC + o] = (v - mu) * r * g[o] + bsh[o];
}

// ---------------- depthwise 3x3 conv (SAME), per frame ----------------
__global__ void k_dwconv(const float* __restrict__ xn, const float* __restrict__ wgt,
                         const float* __restrict__ bias, float* __restrict__ out) {
  int idx = blockIdx.x * 256 + threadIdx.x;       // over NTOK*NC
  int c = idx & (NC - 1);
  int sp = idx >> 7;
  int w = sp % NWW;
  int h = (sp / NWW) % NHH;
  int bd = sp / (NWW * NHH);
  float acc = bias[c];
  #pragma unroll
  for (int kh = 0; kh < 3; kh++) {
    int hh = h + kh - 1;
    if (hh < 0 || hh >= NHH) continue;
    #pragma unroll
    for (int kw = 0; kw < 3; kw++) {
      int ww = w + kw - 1;
      if (ww < 0 || ww >= NWW) continue;
      acc += xn[((bd * NHH + hh) * NWW + ww) * NC + c] * wgt[(kh * 3 + kw) * NC + c];
    }
  }
  out[idx] = acc;
}

// ---------------- tiled f32 GEMM: C[M,N] = A[M,K] * W[N,K]^T (+ epilogues) -----
// MODE 0: qkv  — A rows gathered from xn (windowed order); out -> bf16 Q/K/V head-split, +bias
// MODE 1: proj — A = attn_out (windowed); x1[src] = x[src] + xconv[src] + bias + val (in-place over xconv)
// MODE 2: fc1  — A = xm; gelu(bias+val) -> bf16 hidden
// MODE 3: fc2  — A = bf16 hidden (K=512); out = x1 + bias + val -> f32 d_out
template <int N, int K, int MODE>
__global__ __launch_bounds__(256) void k_gemm(
    const void* __restrict__ Av, const float* __restrict__ Wt,
    const float* __restrict__ bias, const float* __restrict__ res1,
    float* __restrict__ res2rw, void* __restrict__ O0, void* __restrict__ O1,
    void* __restrict__ O2) {
  __shared__ float As[16][64];   // k-major
  __shared__ float Bs[16][64];
  int tid = threadIdx.x;
  int m0 = blockIdx.x * 64, n0 = blockIdx.y * 64;
  int lrow = tid >> 2;          // 0..63
  int lk = (tid & 3) * 4;       // 0,4,8,12
  int arow_src = (MODE == 0) ? win_to_src(m0 + lrow) : (m0 + lrow);
  float acc[4][4];
  #pragma unroll
  for (int i = 0; i < 4; i++)
    #pragma unroll
    for (int j = 0; j < 4; j++) acc[i][j] = 0.f;
  int ty = tid >> 4, tx = tid & 15;
  for (int k0 = 0; k0 < K; k0 += 16) {
    if (MODE == 3) {
      const __hip_bfloat16* A = (const __hip_bfloat16*)Av;
      uint2 u = *(const uint2*)(A + (long)arow_src * K + k0 + lk);
      As[lk + 0][lrow] = __uint_as_float(u.x << 16);
      As[lk + 1][lrow] = __uint_as_float(u.x & 0xffff0000u);
      As[lk + 2][lrow] = __uint_as_float(u.y << 16);
      As[lk + 3][lrow] = __uint_as_float(u.y & 0xffff0000u);
    } else {
      const float* A = (const float*)Av;
      float4 a4 = *(const float4*)(A + (long)arow_src * K + k0 + lk);
      As[lk + 0][lrow] = a4.x;
      As[lk + 1][lrow] = a4.y;
      As[lk + 2][lrow] = a4.z;
      As[lk + 3][lrow] = a4.w;
    }
    {
      float4 b4 = *(const float4*)(Wt + (long)(n0 + lrow) * K + k0 + lk);
      Bs[lk + 0][lrow] = b4.x;
      Bs[lk + 1][lrow] = b4.y;
      Bs[lk + 2][lrow] = b4.z;
      Bs[lk + 3][lrow] = b4.w;
    }
    __syncthreads();
    #pragma unroll
    for (int kk = 0; kk < 16; kk++) {
      float4 a4 = *(const float4*)&As[kk][ty * 4];
      float4 b4 = *(const float4*)&Bs[kk][tx * 4];
      float av[4] = {a4.x, a4.y, a4.z, a4.w};
      float bv[4] = {b4.x, b4.y, b4.z, b4.w};
      #pragma unroll
      for (int i = 0; i < 4; i++)
        #pragma unroll
        for (int j = 0; j < 4; j++) acc[i][j] += av[i] * bv[j];
    }
    __syncthreads();
  }
  #pragma unroll
  for (int i = 0; i < 4; i++) {
    int m = m0 + ty * 4 + i;
    int srcT = 0;
    if constexpr (MODE == 1) srcT = win_to_src(m);
    #pragma unroll
    for (int j = 0; j < 4; j++) {
      int nn = n0 + tx * 4 + j;
      float v = acc[i][j] + bias[nn];
      if constexpr (MODE == 0) {
        int which = nn >> 7;                 // 0=q 1=k 2=v
        int head = (nn & 127) >> 5, dim = nn & 31;
        int win = m / NSEQ, n = m % NSEQ;
        long oidx = ((long)(win * NHEAD + head) * NSEQ + n) * DHEAD + dim;
        __hip_bfloat16 hv = __float2bfloat16(v);
        if (which == 0) ((__hip_bfloat16*)O0)[oidx] = hv;
        else if (which == 1) ((__hip_bfloat16*)O1)[oidx] = hv;
        else ((__hip_bfloat16*)O2)[oidx] = hv;
      } else if constexpr (MODE == 1) {
        long off = (long)srcT * NC + nn;
        float r = res1[off] + res2rw[off];   // x + xconv  (each elem touched by exactly one thread)
        res2rw[off] = r + v;                 // -> x1 in place
      } else if constexpr (MODE == 2) {
        float gl = 0.5f * v * (1.0f + erff(v * 0.70710678118654752440f));
        ((__hip_bfloat16*)O0)[(long)m * NHID + nn] = __float2bfloat16(gl);
      } else {
        ((float*)O0)[(long)m * NC + nn] = res1[(long)m * NC + nn] + v;
      }
    }
  }
}

// ---------------- windowed attention, one block = (window, head) --------------
__global__ __launch_bounds__(256) void k_attn(const __hip_bfloat16* __restrict__ Q,
                                              const __hip_bfloat16* __restrict__ Kk,
                                              const __hip_bfloat16* __restrict__ Vv,
                                              float* __restrict__ aout) {
  int wh = blockIdx.x;              // win*4 + head
  int win = wh >> 2, head = wh & 3;
  __shared__ uint32 Ks[NSEQ * 16];  // bf16 pairs, 25 KB
  __shared__ uint32 Vs[NSEQ * 16];
  const uint32* Kg = (const uint32*)(Kk + (long)wh * NSEQ * DHEAD);
  const uint32* Vg = (const uint32*)(Vv + (long)wh * NSEQ * DHEAD);
  for (int i = threadIdx.x; i < NSEQ * 16; i += 256) {
    Ks[i] = Kg[i];
    Vs[i] = Vg[i];
  }
  __syncthreads();
  const float scale = 0.17677669529663688f;  // 32^-0.5
  for (int r = threadIdx.x; r < NSEQ; r += 256) {
    const uint32* Qr = (const uint32*)(Q + ((long)wh * NSEQ + r) * DHEAD);
    float qv[DHEAD];
    #pragma unroll
    for (int d2 = 0; d2 < 16; d2++) {
      uint32 u = Qr[d2];
      qv[2 * d2]     = __uint_as_float(u << 16) * scale;
      qv[2 * d2 + 1] = __uint_as_float(u & 0xffff0000u) * scale;
    }
    float mmax = -1e30f, l = 0.f;
    float oacc[DHEAD];
    #pragma unroll
    for (int d = 0; d < DHEAD; d++) oacc[d] = 0.f;
    for (int m = 0; m < NSEQ; m++) {
      float s = 0.f;
      #pragma unroll
      for (int d2 = 0; d2 < 16; d2++) {
        uint32 u = Ks[m * 16 + d2];
        s += qv[2 * d2]     * __uint_as_float(u << 16);
        s += qv[2 * d2 + 1] * __uint_as_float(u & 0xffff0000u);
      }
      float nm = fmaxf(mmax, s);
      float corr = __expf(mmax - nm);
      float pe = __expf(s - nm);
      l = l * corr + pe;
      #pragma unroll
      for (int d2 = 0; d2 < 16; d2++) {
        uint32 u = Vs[m * 16 + d2];
        oacc[2 * d2]     = oacc[2 * d2]     * corr + pe * __uint_as_float(u << 16);
        oacc[2 * d2 + 1] = oacc[2 * d2 + 1] * corr + pe * __uint_as_float(u & 0xffff0000u);
      }
      mmax = nm;
    }
    float inv = 1.f / l;
    float* Or = aout + ((long)(win * NSEQ + r)) * NC + head * DHEAD;
    #pragma unroll
    for (int d = 0; d < DHEAD; d++) Or[d] = oacc[d] * inv;
  }
}

extern "C" void kernel_launch(void* const* d_in, const int* in_sizes, int n_in,
                              void* d_out, int out_size, void* d_ws, size_t ws_size,
                              hipStream_t stream) {
  const float* x    = (const float*)d_in[0];
  const float* n1g  = (const float*)d_in[1];
  const float* n1b  = (const float*)d_in[2];
  const float* qkvw = (const float*)d_in[3];
  const float* qkvb = (const float*)d_in[4];
  const float* projw= (const float*)d_in[5];
  const float* projb= (const float*)d_in[6];
  const float* dww  = (const float*)d_in[7];
  const float* dwb  = (const float*)d_in[8];
  const float* n2g  = (const float*)d_in[9];
  const float* n2b  = (const float*)d_in[10];
  const float* fc1w = (const float*)d_in[11];
  const float* fc1b = (const float*)d_in[12];
  const float* fc2w = (const float*)d_in[13];
  const float* fc2b = (const float*)d_in[14];

  const long SZ = (long)NTOK * NC;             // 6,422,528 elems
  float* ws    = (float*)d_ws;
  float* xn    = ws;                            // [0, SZ) f32
  float* xconv = ws + SZ;                       // [SZ, 2SZ) f32, becomes x1 in place
  __hip_bfloat16* Qb = (__hip_bfloat16*)(ws + 2 * SZ);   // bf16, SZ elems
  __hip_bfloat16* Kb = Qb + SZ;
  __hip_bfloat16* Vb = Kb + SZ;
  float* aout = ws;                             // reuse xn slot (dead)
  float* x1   = xconv;
  float* xm   = ws;                             // reuse aout slot (dead after proj)
  __hip_bfloat16* hid = (__hip_bfloat16*)(ws + 2 * SZ);  // reuse QKV region, 2*SZ floats worth

  k_ln<<<NTOK, 128, 0, stream>>>(x, n1g, n1b, xn);
  k_dwconv<<<(NTOK * NC) / 256, 256, 0, stream>>>(xn, dww, dwb, xconv);
  k_gemm<384, 128, 0><<<dim3(784, 6), 256, 0, stream>>>(xn, qkvw, qkvb, nullptr, nullptr, Qb, Kb, Vb);
  k_attn<<<NWIN * NHEAD, 256, 0, stream>>>(Qb, Kb, Vb, aout);
  k_gemm<128, 128, 1><<<dim3(784, 2), 256, 0, stream>>>(aout, projw, projb, x, x1, nullptr, nullptr, nullptr);
  k_ln<<<NTOK, 128, 0, stream>>>(x1, n2g, n2b, xm);
  k_gemm<512, 128, 2><<<dim3(784, 8), 256, 0, stream>>>(xm, fc1w, fc1b, nullptr, nullptr, hid, nullptr, nullptr);
  k_gemm<128, 512, 3><<<dim3(784, 2), 256, 0, stream>>>(hid, fc2w, fc2b, x1, nullptr, d_out, nullptr, nullptr);
}

// Round 2
// 485.712 us; speedup vs baseline: 1.6170x; 1.6170x over previous
//
#include <hip/hip_runtime.h>
#include <hip/hip_bf16.h>

#define NB 2
#define ND 8
#define NHH 56
#define NWW 56
#define NC 128
#define NHEAD 4
#define DHEAD 32
#define NSEQ 392            // 8*7*7
#define NWIN 128            // 2*8*8
#define NTOK (NB*ND*NHH*NWW) // 50176
#define NHID 512
#define EPSV 1e-5f

typedef unsigned int uint32;
typedef __attribute__((ext_vector_type(8))) short bf16x8;
typedef __attribute__((ext_vector_type(4))) float f32x4;

__device__ __forceinline__ short f2bf(float x) {
  __hip_bfloat16 h = __float2bfloat16(x);
  return *reinterpret_cast<short*>(&h);
}

// windowed token index -> source spatial token index
// win = b*64 + gh*8 + gw ; n = d*49 + p*7 + q ; (h,w) = (p*8+gh, q*8+gw)
__device__ __forceinline__ int win_to_src(int grow) {
  int win = grow / NSEQ, n = grow % NSEQ;
  int b = win >> 6, gh = (win >> 3) & 7, gw = win & 7;
  int d = n / 49, rem = n % 49;
  int p = rem / 7, q = rem % 7;
  int h = p * 8 + gh, w = q * 8 + gw;
  return ((b * ND + d) * NHH + h) * NWW + w;
}

// ---------------- LayerNorm (one block = one token row of 128) ----------------
__global__ void k_ln(const float* __restrict__ xin, const float* __restrict__ g,
                     const float* __restrict__ bsh, float* __restrict__ out) {
  int t = blockIdx.x, o = threadIdx.x;
  __shared__ float s1[128], s2[128];
  float v = xin[(long)t * NC + o];
  s1[o] = v; s2[o] = v * v;
  __syncthreads();
  for (int off = 64; off > 0; off >>= 1) {
    if (o < off) { s1[o] += s1[o + off]; s2[o] += s2[o + off]; }
    __syncthreads();
  }
  float mu = s1[0] * (1.0f / NC);
  float var = s2[0] * (1.0f / NC) - mu * mu;
  float r = rsqrtf(var + EPSV);
  out[(long)t * NC + o] = (v - mu) * r * g[o] + bsh[o];
}

// ---------------- depthwise 3x3 conv (SAME), per frame ----------------
__global__ void k_dwconv(const float* __restrict__ xn, const float* __restrict__ wgt,
                         const float* __restrict__ bias, float* __restrict__ out) {
  int idx = blockIdx.x * 256 + threadIdx.x;       // over NTOK*NC
  int c = idx & (NC - 1);
  int sp = idx >> 7;
  int w = sp % NWW;
  int h = (sp / NWW) % NHH;
  int bd = sp / (NWW * NHH);
  float acc = bias[c];
  #pragma unroll
  for (int kh = 0; kh < 3; kh++) {
    int hh = h + kh - 1;
    if (hh < 0 || hh >= NHH) continue;
    #pragma unroll
    for (int kw = 0; kw < 3; kw++) {
      int ww = w + kw - 1;
      if (ww < 0 || ww >= NWW) continue;
      acc += xn[((bd * NHH + hh) * NWW + ww) * NC + c] * wgt[(kh * 3 + kw) * NC + c];
    }
  }
  out[idx] = acc;
}

// ---------------- tiled f32 GEMM: C[M,N] = A[M,K] * W[N,K]^T (+ epilogues) -----
// MODE 0: qkv  — A rows gathered from xn (windowed order); out -> bf16 Q(scaled)/K/Vt, +bias
// MODE 1: proj — A = attn_out (windowed); x1[src] = x[src] + xconv[src] + bias + val
// MODE 2: fc1  — A = xm; gelu(bias+val) -> bf16 hidden
// MODE 3: fc2  — A = bf16 hidden (K=512); out = x1 + bias + val -> f32 d_out
template <int N, int K, int MODE>
__global__ __launch_bounds__(256) void k_gemm(
    const void* __restrict__ Av, const float* __restrict__ Wt,
    const float* __restrict__ bias, const float* __restrict__ res1,
    float* __restrict__ res2rw, void* __restrict__ O0, void* __restrict__ O1,
    void* __restrict__ O2) {
  __shared__ float As[16][64];   // k-major
  __shared__ float Bs[16][64];
  int tid = threadIdx.x;
  int m0 = blockIdx.x * 64, n0 = blockIdx.y * 64;
  int lrow = tid >> 2;          // 0..63
  int lk = (tid & 3) * 4;       // 0,4,8,12
  int arow_src = (MODE == 0) ? win_to_src(m0 + lrow) : (m0 + lrow);
  float acc[4][4];
  #pragma unroll
  for (int i = 0; i < 4; i++)
    #pragma unroll
    for (int j = 0; j < 4; j++) acc[i][j] = 0.f;
  int ty = tid >> 4, tx = tid & 15;
  for (int k0 = 0; k0 < K; k0 += 16) {
    if (MODE == 3) {
      const __hip_bfloat16* A = (const __hip_bfloat16*)Av;
      uint2 u = *(const uint2*)(A + (long)arow_src * K + k0 + lk);
      As[lk + 0][lrow] = __uint_as_float(u.x << 16);
      As[lk + 1][lrow] = __uint_as_float(u.x & 0xffff0000u);
      As[lk + 2][lrow] = __uint_as_float(u.y << 16);
      As[lk + 3][lrow] = __uint_as_float(u.y & 0xffff0000u);
    } else {
      const float* A = (const float*)Av;
      float4 a4 = *(const float4*)(A + (long)arow_src * K + k0 + lk);
      As[lk + 0][lrow] = a4.x;
      As[lk + 1][lrow] = a4.y;
      As[lk + 2][lrow] = a4.z;
      As[lk + 3][lrow] = a4.w;
    }
    {
      float4 b4 = *(const float4*)(Wt + (long)(n0 + lrow) * K + k0 + lk);
      Bs[lk + 0][lrow] = b4.x;
      Bs[lk + 1][lrow] = b4.y;
      Bs[lk + 2][lrow] = b4.z;
      Bs[lk + 3][lrow] = b4.w;
    }
    __syncthreads();
    #pragma unroll
    for (int kk = 0; kk < 16; kk++) {
      float4 a4 = *(const float4*)&As[kk][ty * 4];
      float4 b4 = *(const float4*)&Bs[kk][tx * 4];
      float av[4] = {a4.x, a4.y, a4.z, a4.w};
      float bv[4] = {b4.x, b4.y, b4.z, b4.w};
      #pragma unroll
      for (int i = 0; i < 4; i++)
        #pragma unroll
        for (int j = 0; j < 4; j++) acc[i][j] += av[i] * bv[j];
    }
    __syncthreads();
  }
  #pragma unroll
  for (int i = 0; i < 4; i++) {
    int m = m0 + ty * 4 + i;
    int srcT = 0;
    if constexpr (MODE == 1) srcT = win_to_src(m);
    #pragma unroll
    for (int j = 0; j < 4; j++) {
      int nn = n0 + tx * 4 + j;
      float v = acc[i][j] + bias[nn];
      if constexpr (MODE == 0) {
        int which = nn >> 7;                 // 0=q 1=k 2=v
        int head = (nn & 127) >> 5, dim = nn & 31;
        int win = m / NSEQ, n = m % NSEQ;
        if (which == 0) {
          v *= 0.17677669529663688f;         // pre-scale Q by 32^-0.5
          long oidx = ((long)(win * NHEAD + head) * NSEQ + n) * DHEAD + dim;
          ((__hip_bfloat16*)O0)[oidx] = __float2bfloat16(v);
        } else if (which == 1) {
          long oidx = ((long)(win * NHEAD + head) * NSEQ + n) * DHEAD + dim;
          ((__hip_bfloat16*)O1)[oidx] = __float2bfloat16(v);
        } else {                             // V stored TRANSPOSED: [wh][d][n]
          long oidx = ((long)(win * NHEAD + head) * DHEAD + dim) * NSEQ + n;
          ((__hip_bfloat16*)O2)[oidx] = __float2bfloat16(v);
        }
      } else if constexpr (MODE == 1) {
        long off = (long)srcT * NC + nn;
        float r = res1[off] + res2rw[off];   // x + xconv
        res2rw[off] = r + v;                 // -> x1 in place
      } else if constexpr (MODE == 2) {
        float gl = 0.5f * v * (1.0f + erff(v * 0.70710678118654752440f));
        ((__hip_bfloat16*)O0)[(long)m * NHID + nn] = __float2bfloat16(gl);
      } else {
        ((float*)O0)[(long)m * NC + nn] = res1[(long)m * NC + nn] + v;
      }
    }
  }
}

// ---------------- MFMA windowed attention: one block = (window, head) ---------
// K LDS [416][32] bf16 (rows >=392 zeroed); Vt LDS [32][416] (cols >=392 zeroed);
// per-wave P tile [16][32] bf16 for the C-layout -> A-fragment transpose.
__global__ __launch_bounds__(256) void k_attn_mfma(
    const __hip_bfloat16* __restrict__ Q,   // [wh][n][32], pre-scaled
    const __hip_bfloat16* __restrict__ Kk,  // [wh][n][32]
    const __hip_bfloat16* __restrict__ Vt,  // [wh][32][n]
    float* __restrict__ aout) {
  int wh = blockIdx.x, win = wh >> 2, head = wh & 3;
  __shared__ short Ks[416 * 32];
  __shared__ short Vs[32 * 416];
  __shared__ short Ps[4][16 * 32];
  int tid = threadIdx.x;
  int lane = tid & 63, w = tid >> 6;
  int c16 = lane & 15, g = lane >> 4, g8 = g * 8;

  // ---- stage K (12544 shorts = 1568 uint4) + zero tail rows 392..415 ----
  const uint4* Kg4 = (const uint4*)(Kk + (long)wh * NSEQ * DHEAD);
  uint4* Ks4 = (uint4*)Ks;
  for (int i = tid; i < 1568; i += 256) Ks4[i] = Kg4[i];
  if (tid < 96) Ks4[1568 + tid] = make_uint4(0, 0, 0, 0);
  // ---- stage Vt rows (392 shorts = 98 uint2 per row) + zero col tails ----
  const uint2* Vg2 = (const uint2*)(Vt + (long)wh * DHEAD * NSEQ);
  for (int i = tid; i < 32 * 98; i += 256) {
    int r = i / 98, cq = i - r * 98;
    *(uint2*)&Vs[r * 416 + cq * 4] = Vg2[i];
  }
  for (int i = tid; i < 32 * 6; i += 256) {
    int r = i / 6, cq = i - r * 6;
    *(uint2*)&Vs[r * 416 + 392 + cq * 4] = make_uint2(0, 0);
  }
  __syncthreads();

  const short* Qg = reinterpret_cast<const short*>(Q);
  short* Pw = Ps[w];

  for (int t = w; t < 25; t += 4) {         // 16-row Q tiles; tile 24 half-valid
    int q0 = t * 16;
    int qrow = q0 + c16; if (qrow > NSEQ - 1) qrow = NSEQ - 1;
    bf16x8 qf = *(const bf16x8*)(Qg + ((long)wh * NSEQ + qrow) * DHEAD + g8);
    f32x4 o0 = {0.f, 0.f, 0.f, 0.f}, o1 = {0.f, 0.f, 0.f, 0.f};
    float mrow[4] = {-1e30f, -1e30f, -1e30f, -1e30f};
    float lrow[4] = {0.f, 0.f, 0.f, 0.f};
    for (int c = 0; c < 13; c++) {
      int m0 = c * 32;
      bf16x8 kf0 = *(const bf16x8*)&Ks[(m0 + c16) * 32 + g8];
      bf16x8 kf1 = *(const bf16x8*)&Ks[(m0 + 16 + c16) * 32 + g8];
      f32x4 z = {0.f, 0.f, 0.f, 0.f};
      f32x4 S0 = __builtin_amdgcn_mfma_f32_16x16x32_bf16(qf, kf0, z, 0, 0, 0);
      f32x4 S1 = __builtin_amdgcn_mfma_f32_16x16x32_bf16(qf, kf1, z, 0, 0, 0);
      #pragma unroll
      for (int r = 0; r < 4; r++) {
        float s0 = S0[r], s1 = S1[r];
        if (m0 + c16 >= NSEQ) s0 = -1e30f;        // only triggers on c==12
        if (m0 + 16 + c16 >= NSEQ) s1 = -1e30f;
        float mx = fmaxf(s0, s1);
        mx = fmaxf(mx, __shfl_xor(mx, 1));
        mx = fmaxf(mx, __shfl_xor(mx, 2));
        mx = fmaxf(mx, __shfl_xor(mx, 4));
        mx = fmaxf(mx, __shfl_xor(mx, 8));
        float nm = fmaxf(mrow[r], mx);
        float corr = __expf(mrow[r] - nm);
        mrow[r] = nm;
        float p0 = __expf(s0 - nm), p1 = __expf(s1 - nm);
        float ps = p0 + p1;
        ps += __shfl_xor(ps, 1);
        ps += __shfl_xor(ps, 2);
        ps += __shfl_xor(ps, 4);
        ps += __shfl_xor(ps, 8);
        lrow[r] = lrow[r] * corr + ps;
        o0[r] *= corr;
        o1[r] *= corr;
        int prow = g * 4 + r;                     // C-layout row
        Pw[prow * 32 + c16] = f2bf(p0);
        Pw[prow * 32 + 16 + c16] = f2bf(p1);
      }
      // in-wave fence: P writes (cross-lane) must land before a-frag reads
      asm volatile("s_waitcnt lgkmcnt(0)" ::: "memory");
      bf16x8 pf  = *(const bf16x8*)&Pw[c16 * 32 + g8];
      bf16x8 vf0 = *(const bf16x8*)&Vs[c16 * 416 + m0 + g8];
      bf16x8 vf1 = *(const bf16x8*)&Vs[(16 + c16) * 416 + m0 + g8];
      o0 = __builtin_amdgcn_mfma_f32_16x16x32_bf16(pf, vf0, o0, 0, 0, 0);
      o1 = __builtin_amdgcn_mfma_f32_16x16x32_bf16(pf, vf1, o1, 0, 0, 0);
    }
    #pragma unroll
    for (int r = 0; r < 4; r++) {
      int q = q0 + 4 * g + r;
      if (q < NSEQ) {
        float inv = 1.0f / lrow[r];
        long base = ((long)win * NSEQ + q) * NC + head * DHEAD;
        aout[base + c16] = o0[r] * inv;
        aout[base + 16 + c16] = o1[r] * inv;
      }
    }
  }
}

extern "C" void kernel_launch(void* const* d_in, const int* in_sizes, int n_in,
                              void* d_out, int out_size, void* d_ws, size_t ws_size,
                              hipStream_t stream) {
  const float* x    = (const float*)d_in[0];
  const float* n1g  = (const float*)d_in[1];
  const float* n1b  = (const float*)d_in[2];
  const float* qkvw = (const float*)d_in[3];
  const float* qkvb = (const float*)d_in[4];
  const float* projw= (const float*)d_in[5];
  const float* projb= (const float*)d_in[6];
  const float* dww  = (const float*)d_in[7];
  const float* dwb  = (const float*)d_in[8];
  const float* n2g  = (const float*)d_in[9];
  const float* n2b  = (const float*)d_in[10];
  const float* fc1w = (const float*)d_in[11];
  const float* fc1b = (const float*)d_in[12];
  const float* fc2w = (const float*)d_in[13];
  const float* fc2b = (const float*)d_in[14];

  const long SZ = (long)NTOK * NC;             // 6,422,528 elems
  float* ws    = (float*)d_ws;
  float* xn    = ws;                            // [0, SZ) f32
  float* xconv = ws + SZ;                       // [SZ, 2SZ) f32, becomes x1 in place
  __hip_bfloat16* Qb = (__hip_bfloat16*)(ws + 2 * SZ);   // bf16, SZ elems
  __hip_bfloat16* Kb = Qb + SZ;
  __hip_bfloat16* Vb = Kb + SZ;                 // V transposed per (win,head)
  float* aout = ws;                             // reuse xn slot (dead after qkv)
  float* x1   = xconv;
  float* xm   = ws;                             // reuse aout slot (dead after proj)
  __hip_bfloat16* hid = (__hip_bfloat16*)(ws + 2 * SZ);  // reuse QKV region

  k_ln<<<NTOK, 128, 0, stream>>>(x, n1g, n1b, xn);
  k_dwconv<<<(NTOK * NC) / 256, 256, 0, stream>>>(xn, dww, dwb, xconv);
  k_gemm<384, 128, 0><<<dim3(784, 6), 256, 0, stream>>>(xn, qkvw, qkvb, nullptr, nullptr, Qb, Kb, Vb);
  k_attn_mfma<<<NWIN * NHEAD, 256, 0, stream>>>(Qb, Kb, Vb, aout);
  k_gemm<128, 128, 1><<<dim3(784, 2), 256, 0, stream>>>(aout, projw, projb, x, x1, nullptr, nullptr, nullptr);
  k_ln<<<NTOK, 128, 0, stream>>>(x1, n2g, n2b, xm);
  k_gemm<512, 128, 2><<<dim3(784, 8), 256, 0, stream>>>(xm, fc1w, fc1b, nullptr, nullptr, hid, nullptr, nullptr);
  k_gemm<128, 512, 3><<<dim3(784, 2), 256, 0, stream>>>(hid, fc2w, fc2b, x1, nullptr, d_out, nullptr, nullptr);
}

// Round 3
// 290.949 us; speedup vs baseline: 2.6995x; 1.6694x over previous
//
#include <hip/hip_runtime.h>
#include <hip/hip_bf16.h>

#define NB 2
#define ND 8
#define NHH 56
#define NWW 56
#define NC 128
#define NHEAD 4
#define DHEAD 32
#define NSEQ 392            // 8*7*7
#define NWIN 128            // 2*8*8
#define NTOK (NB*ND*NHH*NWW) // 50176
#define NHID 512
#define EPSV 1e-5f

typedef unsigned int uint32;
typedef __attribute__((ext_vector_type(8))) short bf16x8;
typedef __attribute__((ext_vector_type(4))) float f32x4;

__device__ __forceinline__ short f2bf(float x) {
  __hip_bfloat16 h = __float2bfloat16(x);
  return *reinterpret_cast<short*>(&h);
}
__device__ __forceinline__ float bflo(uint32 u) { return __uint_as_float(u << 16); }
__device__ __forceinline__ float bfhi(uint32 u) { return __uint_as_float(u & 0xffff0000u); }

// windowed token index -> source spatial token index
// win = b*64 + gh*8 + gw ; n = d*49 + p*7 + q ; (h,w) = (p*8+gh, q*8+gw)
__device__ __forceinline__ int win_to_src(int grow) {
  int win = grow / NSEQ, n = grow % NSEQ;
  int b = win >> 6, gh = (win >> 3) & 7, gw = win & 7;
  int d = n / 49, rem = n % 49;
  int p = rem / 7, q = rem % 7;
  int h = p * 8 + gh, w = q * 8 + gw;
  return ((b * ND + d) * NHH + h) * NWW + w;
}

// ---------------- weights -> bf16 (concatenated: qkv|proj|fc1|fc2) -----------
__global__ void k_convw(const float* __restrict__ qkvw, const float* __restrict__ projw,
                        const float* __restrict__ fc1w, const float* __restrict__ fc2w,
                        short* __restrict__ out) {
  int i = blockIdx.x * 256 + threadIdx.x;   // 196608 total
  float v;
  if (i < 49152) v = qkvw[i];
  else if (i < 65536) v = projw[i - 49152];
  else if (i < 131072) v = fc1w[i - 65536];
  else v = fc2w[i - 131072];
  out[i] = f2bf(v);
}

// ---------------- LayerNorm (one block = one token row of 128) -> bf16 --------
__global__ void k_ln(const float* __restrict__ xin, const float* __restrict__ g,
                     const float* __restrict__ bsh, short* __restrict__ out) {
  int t = blockIdx.x, o = threadIdx.x;
  __shared__ float s1[128], s2[128];
  float v = xin[(long)t * NC + o];
  s1[o] = v; s2[o] = v * v;
  __syncthreads();
  for (int off = 64; off > 0; off >>= 1) {
    if (o < off) { s1[o] += s1[o + off]; s2[o] += s2[o + off]; }
    __syncthreads();
  }
  float mu = s1[0] * (1.0f / NC);
  float var = s2[0] * (1.0f / NC) - mu * mu;
  float r = rsqrtf(var + EPSV);
  out[(long)t * NC + o] = f2bf((v - mu) * r * g[o] + bsh[o]);
}

// ---------------- depthwise 3x3 conv (SAME), bf16 in, f32 out, 2 ch/thread ----
__global__ void k_dwconv(const short* __restrict__ xn, const float* __restrict__ wgt,
                         const float* __restrict__ bias, float* __restrict__ out) {
  int idx = blockIdx.x * 256 + threadIdx.x;       // over NTOK*64
  int cp = idx & 63;                               // channel pair
  int sp = idx >> 6;
  int w = sp % NWW;
  int h = (sp / NWW) % NHH;
  int bd = sp / (NWW * NHH);
  float a0 = bias[2 * cp], a1 = bias[2 * cp + 1];
  #pragma unroll
  for (int kh = 0; kh < 3; kh++) {
    int hh = h + kh - 1;
    if (hh < 0 || hh >= NHH) continue;
    #pragma unroll
    for (int kw = 0; kw < 3; kw++) {
      int ww = w + kw - 1;
      if (ww < 0 || ww >= NWW) continue;
      uint32 u = *(const uint32*)(xn + (((long)(bd * NHH + hh) * NWW + ww) << 7) + 2 * cp);
      a0 += bflo(u) * wgt[(kh * 3 + kw) * NC + 2 * cp];
      a1 += bfhi(u) * wgt[(kh * 3 + kw) * NC + 2 * cp + 1];
    }
  }
  *(float2*)(out + ((long)sp << 7) + 2 * cp) = make_float2(a0, a1);
}

// ---------------- MFMA GEMM: C[M,N] = A[M,K] * W[N,K]^T, 128x128 tile ---------
// MODE 0: qkv  — A rows gathered (windowed); out bf16 Q(scaled)/K/Vt
// MODE 1: proj — A windowed; x1[src] = x[src] + xconv[src] + bias + val (scatter)
// MODE 2: fc1  — gelu -> bf16 hid (chunk-local rows)
// MODE 3: fc2  — K=512; d_out[m] = x1[m] + bias + val (f32)
template <int NDIM, int KDIM, int MODE>
__global__ __launch_bounds__(256) void k_gemm_mfma(
    const short* __restrict__ A, const short* __restrict__ Wb,
    const float* __restrict__ bias, const float* __restrict__ res1,
    float* __restrict__ res2rw, void* __restrict__ O0, void* __restrict__ O1,
    void* __restrict__ O2, int m_base) {
  __shared__ char As[32768];
  __shared__ char Bs[32768];
  __shared__ int asrc[128];
  int tid = threadIdx.x;
  int m0 = blockIdx.x * 128 + m_base;
  int n0 = blockIdx.y * 128;
  int lane = tid & 63, w = tid >> 6;
  int wm = w & 1, wn = w >> 1;
  int c16 = lane & 15, g = lane >> 4, g8 = g * 8;

  if constexpr (MODE == 0 || MODE == 1) {
    if (tid < 128) asrc[tid] = win_to_src(m0 + tid);
  }
  if constexpr (MODE == 0) __syncthreads();

  f32x4 acc[4][4];
  #pragma unroll
  for (int i = 0; i < 4; i++)
    #pragma unroll
    for (int j = 0; j < 4; j++) acc[i][j] = f32x4{0.f, 0.f, 0.f, 0.f};

  const int KSTEPS = KDIM / 128;
  for (int ks = 0; ks < KSTEPS; ks++) {
    int k0 = ks * 128;
    if (ks > 0) __syncthreads();
    #pragma unroll
    for (int i = 0; i < 8; i++) {
      int idx = tid + i * 256;
      int row = idx >> 4, colq = idx & 15;
      long arow;
      if constexpr (MODE == 0) arow = asrc[row];
      else if constexpr (MODE == 3) arow = m0 + row - m_base;
      else arow = m0 + row;
      uint4 va = *(const uint4*)(A + arow * KDIM + k0 + colq * 8);
      int b = (row << 8) + (colq << 4); b ^= ((row & 7) << 4);
      *(uint4*)(As + b) = va;
      uint4 vb = *(const uint4*)(Wb + (long)(n0 + row) * KDIM + k0 + colq * 8);
      *(uint4*)(Bs + b) = vb;
    }
    __syncthreads();
    #pragma unroll
    for (int kk = 0; kk < 4; kk++) {
      bf16x8 af[4], bfr[4];
      #pragma unroll
      for (int i = 0; i < 4; i++) {
        int ra = wm * 64 + i * 16 + c16;
        int ba = (ra << 8) + ((g + kk * 4) << 4); ba ^= ((ra & 7) << 4);
        af[i] = *(const bf16x8*)(As + ba);
        int rb = wn * 64 + i * 16 + c16;
        int bb = (rb << 8) + ((g + kk * 4) << 4); bb ^= ((rb & 7) << 4);
        bfr[i] = *(const bf16x8*)(Bs + bb);
      }
      #pragma unroll
      for (int i = 0; i < 4; i++)
        #pragma unroll
        for (int j = 0; j < 4; j++)
          acc[i][j] = __builtin_amdgcn_mfma_f32_16x16x32_bf16(af[i], bfr[j], acc[i][j], 0, 0, 0);
    }
  }

  #pragma unroll
  for (int i = 0; i < 4; i++) {
    int gmb = m0 + wm * 64 + i * 16 + g * 4;
    #pragma unroll
    for (int j = 0; j < 4; j++) {
      int n = n0 + wn * 64 + j * 16 + c16;
      float bj = bias[n];
      #pragma unroll
      for (int r = 0; r < 4; r++) {
        int m = gmb + r;
        float v = acc[i][j][r] + bj;
        if constexpr (MODE == 0) {
          int which = n >> 7;                 // 0=q 1=k 2=v
          int head = (n & 127) >> 5, dim = n & 31;
          int win = m / NSEQ, tok = m % NSEQ;
          if (which == 0) {
            long oidx = ((long)(win * NHEAD + head) * NSEQ + tok) * DHEAD + dim;
            ((short*)O0)[oidx] = f2bf(v * 0.17677669529663688f);
          } else if (which == 1) {
            long oidx = ((long)(win * NHEAD + head) * NSEQ + tok) * DHEAD + dim;
            ((short*)O1)[oidx] = f2bf(v);
          } else {                            // V transposed: [wh][d][n]
            long oidx = ((long)(win * NHEAD + head) * DHEAD + dim) * NSEQ + tok;
            ((short*)O2)[oidx] = f2bf(v);
          }
        } else if constexpr (MODE == 1) {
          long off = ((long)asrc[m - m0] << 7) + n;
          res2rw[off] = res1[off] + res2rw[off] + v;
        } else if constexpr (MODE == 2) {
          float gl = 0.5f * v * (1.0f + erff(v * 0.70710678118654752440f));
          ((short*)O0)[((long)(m - m_base) << 9) + n] = f2bf(gl);
        } else {
          ((float*)O0)[((long)m << 7) + n] = res1[((long)m << 7) + n] + v;
        }
      }
    }
  }
}

// ---------------- MFMA windowed attention: one block = (window, head) ---------
__global__ __launch_bounds__(256) void k_attn_mfma(
    const short* __restrict__ Q,   // [wh][n][32], pre-scaled
    const short* __restrict__ Kk,  // [wh][n][32]
    const short* __restrict__ Vt,  // [wh][32][n]
    short* __restrict__ aout) {
  int wh = blockIdx.x, win = wh >> 2, head = wh & 3;
  __shared__ short Ks[416 * 32];
  __shared__ short Vs[32 * 416];
  __shared__ short Ps[4][16 * 32];
  int tid = threadIdx.x;
  int lane = tid & 63, w = tid >> 6;
  int c16 = lane & 15, g = lane >> 4, g8 = g * 8;

  const uint4* Kg4 = (const uint4*)(Kk + (long)wh * NSEQ * DHEAD);
  uint4* Ks4 = (uint4*)Ks;
  for (int i = tid; i < 1568; i += 256) Ks4[i] = Kg4[i];
  if (tid < 96) Ks4[1568 + tid] = make_uint4(0, 0, 0, 0);
  const uint2* Vg2 = (const uint2*)(Vt + (long)wh * DHEAD * NSEQ);
  for (int i = tid; i < 32 * 98; i += 256) {
    int r = i / 98, cq = i - r * 98;
    *(uint2*)&Vs[r * 416 + cq * 4] = Vg2[i];
  }
  for (int i = tid; i < 32 * 6; i += 256) {
    int r = i / 6, cq = i - r * 6;
    *(uint2*)&Vs[r * 416 + 392 + cq * 4] = make_uint2(0, 0);
  }
  __syncthreads();

  short* Pw = Ps[w];
  for (int t = w; t < 25; t += 4) {
    int q0 = t * 16;
    int qrow = q0 + c16; if (qrow > NSEQ - 1) qrow = NSEQ - 1;
    bf16x8 qf = *(const bf16x8*)(Q + ((long)wh * NSEQ + qrow) * DHEAD + g8);
    f32x4 o0 = {0.f, 0.f, 0.f, 0.f}, o1 = {0.f, 0.f, 0.f, 0.f};
    float mrow[4] = {-1e30f, -1e30f, -1e30f, -1e30f};
    float lrow[4] = {0.f, 0.f, 0.f, 0.f};
    for (int c = 0; c < 13; c++) {
      int m0 = c * 32;
      bf16x8 kf0 = *(const bf16x8*)&Ks[(m0 + c16) * 32 + g8];
      bf16x8 kf1 = *(const bf16x8*)&Ks[(m0 + 16 + c16) * 32 + g8];
      f32x4 z = {0.f, 0.f, 0.f, 0.f};
      f32x4 S0 = __builtin_amdgcn_mfma_f32_16x16x32_bf16(qf, kf0, z, 0, 0, 0);
      f32x4 S1 = __builtin_amdgcn_mfma_f32_16x16x32_bf16(qf, kf1, z, 0, 0, 0);
      #pragma unroll
      for (int r = 0; r < 4; r++) {
        float s0 = S0[r], s1 = S1[r];
        if (m0 + c16 >= NSEQ) s0 = -1e30f;
        if (m0 + 16 + c16 >= NSEQ) s1 = -1e30f;
        float mx = fmaxf(s0, s1);
        mx = fmaxf(mx, __shfl_xor(mx, 1));
        mx = fmaxf(mx, __shfl_xor(mx, 2));
        mx = fmaxf(mx, __shfl_xor(mx, 4));
        mx = fmaxf(mx, __shfl_xor(mx, 8));
        float nm = fmaxf(mrow[r], mx);
        float corr = __expf(mrow[r] - nm);
        mrow[r] = nm;
        float p0 = __expf(s0 - nm), p1 = __expf(s1 - nm);
        float ps = p0 + p1;
        ps += __shfl_xor(ps, 1);
        ps += __shfl_xor(ps, 2);
        ps += __shfl_xor(ps, 4);
        ps += __shfl_xor(ps, 8);
        lrow[r] = lrow[r] * corr + ps;
        o0[r] *= corr;
        o1[r] *= corr;
        int prow = g * 4 + r;
        Pw[prow * 32 + c16] = f2bf(p0);
        Pw[prow * 32 + 16 + c16] = f2bf(p1);
      }
      asm volatile("s_waitcnt lgkmcnt(0)" ::: "memory");
      bf16x8 pf  = *(const bf16x8*)&Pw[c16 * 32 + g8];
      bf16x8 vf0 = *(const bf16x8*)&Vs[c16 * 416 + m0 + g8];
      bf16x8 vf1 = *(const bf16x8*)&Vs[(16 + c16) * 416 + m0 + g8];
      o0 = __builtin_amdgcn_mfma_f32_16x16x32_bf16(pf, vf0, o0, 0, 0, 0);
      o1 = __builtin_amdgcn_mfma_f32_16x16x32_bf16(pf, vf1, o1, 0, 0, 0);
    }
    #pragma unroll
    for (int r = 0; r < 4; r++) {
      int q = q0 + 4 * g + r;
      if (q < NSEQ) {
        float inv = 1.0f / lrow[r];
        long base = ((long)win * NSEQ + q) * NC + head * DHEAD;
        aout[base + c16] = f2bf(o0[r] * inv);
        aout[base + 16 + c16] = f2bf(o1[r] * inv);
      }
    }
  }
}

extern "C" void kernel_launch(void* const* d_in, const int* in_sizes, int n_in,
                              void* d_out, int out_size, void* d_ws, size_t ws_size,
                              hipStream_t stream) {
  const float* x    = (const float*)d_in[0];
  const float* n1g  = (const float*)d_in[1];
  const float* n1b  = (const float*)d_in[2];
  const float* qkvw = (const float*)d_in[3];
  const float* qkvb = (const float*)d_in[4];
  const float* projw= (const float*)d_in[5];
  const float* projb= (const float*)d_in[6];
  const float* dww  = (const float*)d_in[7];
  const float* dwb  = (const float*)d_in[8];
  const float* n2g  = (const float*)d_in[9];
  const float* n2b  = (const float*)d_in[10];
  const float* fc1w = (const float*)d_in[11];
  const float* fc1b = (const float*)d_in[12];
  const float* fc2w = (const float*)d_in[13];
  const float* fc2b = (const float*)d_in[14];

  const long SZ = (long)NTOK * NC;             // 6,422,528
  char* ws = (char*)d_ws;
  // byte layout (peak 77.5 MB, < 90 MB proven available):
  short* wb_q = (short*)(ws + 0);              // 49152
  short* wb_p = wb_q + 49152;                  // 16384
  short* wb_1 = wb_p + 16384;                  // 65536
  short* wb_2 = wb_1 + 65536;                  // 65536  (end 393216 B)
  short* xnb   = (short*)(ws + 393216);        // SZ bf16
  float* xconv = (float*)(ws + 13238272);      // SZ f32 -> becomes x1
  short* Qb    = (short*)(ws + 38928384);      // SZ bf16
  short* Kb    = (short*)(ws + 51773440);      // SZ bf16
  short* Vb    = (short*)(ws + 64618496);      // SZ bf16 (end 77463552)
  short* aoutb = xnb;                          // reuse (xn dead after qkv)
  float* x1    = xconv;
  short* xmb   = Qb;                           // reuse (Q dead after attn)
  short* hid   = Kb;                           // 25088*512 bf16 = K+V slots

  k_convw<<<768, 256, 0, stream>>>(qkvw, projw, fc1w, fc2w, wb_q);
  k_ln<<<NTOK, 128, 0, stream>>>(x, n1g, n1b, xnb);
  k_dwconv<<<(NTOK * 64) / 256, 256, 0, stream>>>(xnb, dww, dwb, xconv);
  k_gemm_mfma<384, 128, 0><<<dim3(392, 3), 256, 0, stream>>>(
      xnb, wb_q, qkvb, nullptr, nullptr, Qb, Kb, Vb, 0);
  k_attn_mfma<<<NWIN * NHEAD, 256, 0, stream>>>(Qb, Kb, Vb, aoutb);
  k_gemm_mfma<128, 128, 1><<<dim3(392, 1), 256, 0, stream>>>(
      aoutb, wb_p, projb, x, x1, nullptr, nullptr, nullptr, 0);
  k_ln<<<NTOK, 128, 0, stream>>>(x1, n2g, n2b, xmb);
  for (int c = 0; c < 2; c++) {
    int m_base = c * 25088;
    k_gemm_mfma<512, 128, 2><<<dim3(196, 4), 256, 0, stream>>>(
        xmb, wb_1, fc1b, nullptr, nullptr, hid, nullptr, nullptr, m_base);
    k_gemm_mfma<128, 512, 3><<<dim3(196, 1), 256, 0, stream>>>(
        hid, wb_2, fc2b, x1, nullptr, d_out, nullptr, nullptr, m_base);
  }
}

// Round 4
// 234.548 us; speedup vs baseline: 3.3486x; 1.2405x over previous
//
#include <hip/hip_runtime.h>
#include <hip/hip_bf16.h>

#define NB 2
#define ND 8
#define NHH 56
#define NWW 56
#define NC 128
#define NHEAD 4
#define DHEAD 32
#define NSEQ 392            // 8*7*7
#define NWIN 128            // 2*8*8
#define NTOK (NB*ND*NHH*NWW) // 50176
#define NHID 512
#define EPSV 1e-5f

typedef unsigned int uint32;
typedef __attribute__((ext_vector_type(8))) short bf16x8;
typedef __attribute__((ext_vector_type(4))) float f32x4;
typedef __attribute__((ext_vector_type(16))) float f32x16;

__device__ __forceinline__ short f2bf(float x) {
  __hip_bfloat16 h = __float2bfloat16(x);
  return *reinterpret_cast<short*>(&h);
}
__device__ __forceinline__ float bflo(uint32 u) { return __uint_as_float(u << 16); }
__device__ __forceinline__ float bfhi(uint32 u) { return __uint_as_float(u & 0xffff0000u); }

// windowed token index -> source spatial token index
// win = b*64 + gh*8 + gw ; n = d*49 + p*7 + q ; (h,w) = (p*8+gh, q*8+gw)
__device__ __forceinline__ int win_to_src(int grow) {
  int win = grow / NSEQ, n = grow % NSEQ;
  int b = win >> 6, gh = (win >> 3) & 7, gw = win & 7;
  int d = n / 49, rem = n % 49;
  int p = rem / 7, q = rem % 7;
  int h = p * 8 + gh, w = q * 8 + gw;
  return ((b * ND + d) * NHH + h) * NWW + w;
}

// ---------------- weights -> bf16 (concatenated: qkv|proj|fc1|fc2) -----------
__global__ void k_convw(const float* __restrict__ qkvw, const float* __restrict__ projw,
                        const float* __restrict__ fc1w, const float* __restrict__ fc2w,
                        short* __restrict__ out) {
  int i = blockIdx.x * 256 + threadIdx.x;   // 196608 total
  float v;
  if (i < 49152) v = qkvw[i];
  else if (i < 65536) v = projw[i - 49152];
  else if (i < 131072) v = fc1w[i - 65536];
  else v = fc2w[i - 131072];
  out[i] = f2bf(v);
}

// ---------------- LayerNorm (one block = one token row of 128) -> bf16 --------
__global__ void k_ln(const float* __restrict__ xin, const float* __restrict__ g,
                     const float* __restrict__ bsh, short* __restrict__ out) {
  int t = blockIdx.x, o = threadIdx.x;
  __shared__ float s1[128], s2[128];
  float v = xin[(long)t * NC + o];
  s1[o] = v; s2[o] = v * v;
  __syncthreads();
  for (int off = 64; off > 0; off >>= 1) {
    if (o < off) { s1[o] += s1[o + off]; s2[o] += s2[o + off]; }
    __syncthreads();
  }
  float mu = s1[0] * (1.0f / NC);
  float var = s2[0] * (1.0f / NC) - mu * mu;
  float r = rsqrtf(var + EPSV);
  out[(long)t * NC + o] = f2bf((v - mu) * r * g[o] + bsh[o]);
}

// ---------------- depthwise 3x3 conv (SAME), bf16 in, f32 out, 2 ch/thread ----
__global__ void k_dwconv(const short* __restrict__ xn, const float* __restrict__ wgt,
                         const float* __restrict__ bias, float* __restrict__ out) {
  int idx = blockIdx.x * 256 + threadIdx.x;       // over NTOK*64
  int cp = idx & 63;                               // channel pair
  int sp = idx >> 6;
  int w = sp % NWW;
  int h = (sp / NWW) % NHH;
  int bd = sp / (NWW * NHH);
  float a0 = bias[2 * cp], a1 = bias[2 * cp + 1];
  #pragma unroll
  for (int kh = 0; kh < 3; kh++) {
    int hh = h + kh - 1;
    if (hh < 0 || hh >= NHH) continue;
    #pragma unroll
    for (int kw = 0; kw < 3; kw++) {
      int ww = w + kw - 1;
      if (ww < 0 || ww >= NWW) continue;
      uint32 u = *(const uint32*)(xn + (((long)(bd * NHH + hh) * NWW + ww) << 7) + 2 * cp);
      a0 += bflo(u) * wgt[(kh * 3 + kw) * NC + 2 * cp];
      a1 += bfhi(u) * wgt[(kh * 3 + kw) * NC + 2 * cp + 1];
    }
  }
  *(float2*)(out + ((long)sp << 7) + 2 * cp) = make_float2(a0, a1);
}

// ---------------- MFMA GEMM: C[M,N] = A[M,K] * W[N,K]^T, 128x128 tile ---------
template <int NDIM, int KDIM, int MODE>
__global__ __launch_bounds__(256) void k_gemm_mfma(
    const short* __restrict__ A, const short* __restrict__ Wb,
    const float* __restrict__ bias, const float* __restrict__ res1,
    float* __restrict__ res2rw, void* __restrict__ O0, void* __restrict__ O1,
    void* __restrict__ O2, int m_base) {
  __shared__ char As[32768];
  __shared__ char Bs[32768];
  __shared__ int asrc[128];
  int tid = threadIdx.x;
  int m0 = blockIdx.x * 128 + m_base;
  int n0 = blockIdx.y * 128;
  int lane = tid & 63, w = tid >> 6;
  int wm = w & 1, wn = w >> 1;
  int c16 = lane & 15, g = lane >> 4, g8 = g * 8;

  if constexpr (MODE == 0 || MODE == 1) {
    if (tid < 128) asrc[tid] = win_to_src(m0 + tid);
  }
  if constexpr (MODE == 0) __syncthreads();

  f32x4 acc[4][4];
  #pragma unroll
  for (int i = 0; i < 4; i++)
    #pragma unroll
    for (int j = 0; j < 4; j++) acc[i][j] = f32x4{0.f, 0.f, 0.f, 0.f};

  const int KSTEPS = KDIM / 128;
  for (int ks = 0; ks < KSTEPS; ks++) {
    int k0 = ks * 128;
    if (ks > 0) __syncthreads();
    #pragma unroll
    for (int i = 0; i < 8; i++) {
      int idx = tid + i * 256;
      int row = idx >> 4, colq = idx & 15;
      long arow;
      if constexpr (MODE == 0) arow = asrc[row];
      else if constexpr (MODE == 3) arow = m0 + row - m_base;
      else arow = m0 + row;
      uint4 va = *(const uint4*)(A + arow * KDIM + k0 + colq * 8);
      int b = (row << 8) + (colq << 4); b ^= ((row & 7) << 4);
      *(uint4*)(As + b) = va;
      uint4 vb = *(const uint4*)(Wb + (long)(n0 + row) * KDIM + k0 + colq * 8);
      *(uint4*)(Bs + b) = vb;
    }
    __syncthreads();
    #pragma unroll
    for (int kk = 0; kk < 4; kk++) {
      bf16x8 af[4], bfr[4];
      #pragma unroll
      for (int i = 0; i < 4; i++) {
        int ra = wm * 64 + i * 16 + c16;
        int ba = (ra << 8) + ((g + kk * 4) << 4); ba ^= ((ra & 7) << 4);
        af[i] = *(const bf16x8*)(As + ba);
        int rb = wn * 64 + i * 16 + c16;
        int bb = (rb << 8) + ((g + kk * 4) << 4); bb ^= ((rb & 7) << 4);
        bfr[i] = *(const bf16x8*)(Bs + bb);
      }
      #pragma unroll
      for (int i = 0; i < 4; i++)
        #pragma unroll
        for (int j = 0; j < 4; j++)
          acc[i][j] = __builtin_amdgcn_mfma_f32_16x16x32_bf16(af[i], bfr[j], acc[i][j], 0, 0, 0);
    }
  }

  #pragma unroll
  for (int i = 0; i < 4; i++) {
    int gmb = m0 + wm * 64 + i * 16 + g * 4;
    #pragma unroll
    for (int j = 0; j < 4; j++) {
      int n = n0 + wn * 64 + j * 16 + c16;
      float bj = bias[n];
      #pragma unroll
      for (int r = 0; r < 4; r++) {
        int m = gmb + r;
        float v = acc[i][j][r] + bj;
        if constexpr (MODE == 0) {
          int which = n >> 7;                 // 0=q 1=k 2=v
          int head = (n & 127) >> 5, dim = n & 31;
          int win = m / NSEQ, tok = m % NSEQ;
          if (which == 0) {
            long oidx = ((long)(win * NHEAD + head) * NSEQ + tok) * DHEAD + dim;
            ((short*)O0)[oidx] = f2bf(v * 0.17677669529663688f);
          } else if (which == 1) {
            long oidx = ((long)(win * NHEAD + head) * NSEQ + tok) * DHEAD + dim;
            ((short*)O1)[oidx] = f2bf(v);
          } else {                            // V transposed: [wh][d][n]
            long oidx = ((long)(win * NHEAD + head) * DHEAD + dim) * NSEQ + tok;
            ((short*)O2)[oidx] = f2bf(v);
          }
        } else if constexpr (MODE == 1) {
          long off = ((long)asrc[m - m0] << 7) + n;
          res2rw[off] = res1[off] + res2rw[off] + v;
        } else if constexpr (MODE == 2) {
          float gl = 0.5f * v * (1.0f + erff(v * 0.70710678118654752440f));
          ((short*)O0)[((long)(m - m_base) << 9) + n] = f2bf(gl);
        } else {
          ((float*)O0)[((long)m << 7) + n] = res1[((long)m << 7) + n] + v;
        }
      }
    }
  }
}

// ---------------- swapped-operand 32x32 MFMA attention ------------------------
// One block = (window, head). S^T = mfma32(K, Q): lane owns q = lane&31, 16 k in
// regs (k = (r&3)+8*(r>>2)+4*(lane>>5)); partner lane^32 holds the other 16.
// Softmax fully in-register (2 shfl_xor(32)/chunk); P -> PV B-operand via
// cvt_pk_bf16 + permlane32_swap; O^T = mfma32(V^T, P^T) keeps accum per-lane-q.
__global__ __launch_bounds__(256) void k_attn_mfma(
    const short* __restrict__ Q,   // [wh][n][32], pre-scaled
    const short* __restrict__ Kk,  // [wh][n][32]
    const short* __restrict__ Vt,  // [wh][32][n]
    short* __restrict__ aout) {    // [win*392+q][128] bf16
  int wh = blockIdx.x, win = wh >> 2, head = wh & 3;
  __shared__ short Ks[NSEQ * 32];        // XOR-swizzled rows, 64 B stride
  __shared__ short Vs[32 * 408];         // stride 408 shorts; cols 392..407 zero
  int tid = threadIdx.x;
  int lane = tid & 63, w = tid >> 6;
  int ql = lane & 31, h = lane >> 5;

  // stage K (1568 uint4), swizzled: byte ^= ((row&7)<<4), row = byte>>6
  const uint4* Kg4 = (const uint4*)(Kk + (long)wh * NSEQ * DHEAD);
  for (int i = tid; i < 1568; i += 256) {
    int b = i * 16; b ^= ((b >> 6) & 7) << 4;
    *(uint4*)((char*)Ks + b) = Kg4[i];
  }
  // stage V^T rows (98 uint2/row) + zero pad cols 392..407
  const uint2* Vg2 = (const uint2*)(Vt + (long)wh * DHEAD * NSEQ);
  for (int i = tid; i < 32 * 98; i += 256) {
    int r = i / 98, cq = i - r * 98;
    *(uint2*)&Vs[r * 408 + cq * 4] = Vg2[i];
  }
  if (tid < 128) {
    int r = tid >> 2, cq = tid & 3;
    *(uint2*)&Vs[r * 408 + 392 + cq * 4] = make_uint2(0, 0);
  }
  __syncthreads();

  for (int t = w; t < 13; t += 4) {      // 32-row q tiles; tile 12 has 8 valid
    int q0 = t * 32;
    int qrow = q0 + ql; if (qrow > NSEQ - 1) qrow = NSEQ - 1;
    const short* Qr = Q + ((long)wh * NSEQ + qrow) * DHEAD;
    bf16x8 qf0 = *(const bf16x8*)(Qr + h * 8);        // d 0..15 slice
    bf16x8 qf1 = *(const bf16x8*)(Qr + 16 + h * 8);   // d 16..31 slice
    f32x16 o;
    #pragma unroll
    for (int r = 0; r < 16; r++) o[r] = 0.f;
    float mrun = -1e30f, lrun = 0.f;

    for (int c = 0; c < 13; c++) {
      int kb = c * 32;
      // ---- S^T = K * Q^T (2 k-steps over d) ----
      int krow = kb + ql;
      int sw = (krow & 7) << 4;
      int b0 = krow * 64 + h * 16;
      bf16x8 kf0 = *(const bf16x8*)((char*)Ks + (b0 ^ sw));
      bf16x8 kf1 = *(const bf16x8*)((char*)Ks + ((b0 + 32) ^ sw));
      f32x16 st;
      #pragma unroll
      for (int r = 0; r < 16; r++) st[r] = 0.f;
      st = __builtin_amdgcn_mfma_f32_32x32x16_bf16(kf0, qf0, st, 0, 0, 0);
      st = __builtin_amdgcn_mfma_f32_32x32x16_bf16(kf1, qf1, st, 0, 0, 0);
      if (c == 12) {                       // keys >= 392 invalid (regs r>=4)
        #pragma unroll
        for (int r = 4; r < 16; r++) st[r] = -1e30f;
      }
      // ---- in-register online softmax (per-lane q row) ----
      float pmax = st[0];
      #pragma unroll
      for (int r = 1; r < 16; r++) pmax = fmaxf(pmax, st[r]);
      pmax = fmaxf(pmax, __shfl_xor(pmax, 32));
      float nm = fmaxf(mrun, pmax);
      float corr = __expf(mrun - nm);
      mrun = nm;
      float psum = 0.f;
      #pragma unroll
      for (int r = 0; r < 16; r++) { st[r] = __expf(st[r] - nm); psum += st[r]; }
      psum += __shfl_xor(psum, 32);
      lrun = lrun * corr + psum;
      #pragma unroll
      for (int r = 0; r < 16; r++) o[r] *= corr;
      // ---- P^T B-frags via cvt_pk + permlane32_swap; PV (2 k-steps) ----
      #pragma unroll
      for (int s = 0; s < 2; s++) {
        if (s == 1 && c == 12) break;      // keys 400..415 all zero
        uint32 z0, z1, z2, z3;
        float p0 = st[8 * s + 0], p1 = st[8 * s + 1], p2 = st[8 * s + 2], p3 = st[8 * s + 3];
        float p4 = st[8 * s + 4], p5 = st[8 * s + 5], p6 = st[8 * s + 6], p7 = st[8 * s + 7];
        asm("v_cvt_pk_bf16_f32 %0, %1, %2" : "=v"(z0) : "v"(p0), "v"(p1));
        asm("v_cvt_pk_bf16_f32 %0, %1, %2" : "=v"(z1) : "v"(p2), "v"(p3));
        asm("v_cvt_pk_bf16_f32 %0, %1, %2" : "=v"(z2) : "v"(p4), "v"(p5));
        asm("v_cvt_pk_bf16_f32 %0, %1, %2" : "=v"(z3) : "v"(p6), "v"(p7));
        asm("v_permlane32_swap_b32 %0, %1" : "+v"(z0), "+v"(z2));  // -> frag dw0, dw2
        asm("v_permlane32_swap_b32 %0, %1" : "+v"(z1), "+v"(z3));  // -> frag dw1, dw3
        union { uint32 u[4]; bf16x8 v; } pb;
        pb.u[0] = z0; pb.u[1] = z1; pb.u[2] = z2; pb.u[3] = z3;
        bf16x8 vf = *(const bf16x8*)&Vs[ql * 408 + kb + 16 * s + 8 * h];
        o = __builtin_amdgcn_mfma_f32_32x32x16_bf16(vf, pb.v, o, 0, 0, 0);
      }
    }
    // ---- normalize + store O (lane q = q0+ql, 16 d values) ----
    if (q0 + ql < NSEQ) {
      float inv = 1.0f / lrun;
      long base = ((long)win * NSEQ + q0 + ql) * NC + head * DHEAD;
      #pragma unroll
      for (int rr = 0; rr < 8; rr++) {
        int r = 2 * rr;
        int d = (r & 3) + 8 * (r >> 2) + 4 * h;
        float a0 = o[r] * inv, a1 = o[r + 1] * inv;
        uint32 pk;
        asm("v_cvt_pk_bf16_f32 %0, %1, %2" : "=v"(pk) : "v"(a0), "v"(a1));
        *(uint32*)(aout + base + d) = pk;
      }
    }
  }
}

extern "C" void kernel_launch(void* const* d_in, const int* in_sizes, int n_in,
                              void* d_out, int out_size, void* d_ws, size_t ws_size,
                              hipStream_t stream) {
  const float* x    = (const float*)d_in[0];
  const float* n1g  = (const float*)d_in[1];
  const float* n1b  = (const float*)d_in[2];
  const float* qkvw = (const float*)d_in[3];
  const float* qkvb = (const float*)d_in[4];
  const float* projw= (const float*)d_in[5];
  const float* projb= (const float*)d_in[6];
  const float* dww  = (const float*)d_in[7];
  const float* dwb  = (const float*)d_in[8];
  const float* n2g  = (const float*)d_in[9];
  const float* n2b  = (const float*)d_in[10];
  const float* fc1w = (const float*)d_in[11];
  const float* fc1b = (const float*)d_in[12];
  const float* fc2w = (const float*)d_in[13];
  const float* fc2b = (const float*)d_in[14];

  const long SZ = (long)NTOK * NC;             // 6,422,528
  char* ws = (char*)d_ws;
  short* wb_q = (short*)(ws + 0);              // 49152
  short* wb_p = wb_q + 49152;                  // 16384
  short* wb_1 = wb_p + 16384;                  // 65536
  short* wb_2 = wb_1 + 65536;                  // 65536  (end 393216 B)
  short* xnb   = (short*)(ws + 393216);        // SZ bf16
  float* xconv = (float*)(ws + 13238272);      // SZ f32 -> becomes x1
  short* Qb    = (short*)(ws + 38928384);      // SZ bf16
  short* Kb    = (short*)(ws + 51773440);      // SZ bf16
  short* Vb    = (short*)(ws + 64618496);      // SZ bf16 (end 77463552)
  short* aoutb = xnb;                          // reuse (xn dead after qkv)
  float* x1    = xconv;
  short* xmb   = Qb;                           // reuse (Q dead after attn)
  short* hid   = Kb;                           // 25088*512 bf16 = K+V slots

  k_convw<<<768, 256, 0, stream>>>(qkvw, projw, fc1w, fc2w, wb_q);
  k_ln<<<NTOK, 128, 0, stream>>>(x, n1g, n1b, xnb);
  k_dwconv<<<(NTOK * 64) / 256, 256, 0, stream>>>(xnb, dww, dwb, xconv);
  k_gemm_mfma<384, 128, 0><<<dim3(392, 3), 256, 0, stream>>>(
      xnb, wb_q, qkvb, nullptr, nullptr, Qb, Kb, Vb, 0);
  k_attn_mfma<<<NWIN * NHEAD, 256, 0, stream>>>(Qb, Kb, Vb, aoutb);
  k_gemm_mfma<128, 128, 1><<<dim3(392, 1), 256, 0, stream>>>(
      aoutb, wb_p, projb, x, x1, nullptr, nullptr, nullptr, 0);
  k_ln<<<NTOK, 128, 0, stream>>>(x1, n2g, n2b, xmb);
  for (int c = 0; c < 2; c++) {
    int m_base = c * 25088;
    k_gemm_mfma<512, 128, 2><<<dim3(196, 4), 256, 0, stream>>>(
        xmb, wb_1, fc1b, nullptr, nullptr, hid, nullptr, nullptr, m_base);
    k_gemm_mfma<128, 512, 3><<<dim3(196, 1), 256, 0, stream>>>(
        hid, wb_2, fc2b, x1, nullptr, d_out, nullptr, nullptr, m_base);
  }
}

// Round 5
// 187.161 us; speedup vs baseline: 4.1964x; 1.2532x over previous
//
#include <hip/hip_runtime.h>
#include <hip/hip_bf16.h>

#define NB 2
#define ND 8
#define NHH 56
#define NWW 56
#define NC 128
#define NHEAD 4
#define DHEAD 32
#define NSEQ 392            // 8*7*7
#define NWIN 128            // 2*8*8
#define NTOK (NB*ND*NHH*NWW) // 50176
#define NHID 512
#define EPSV 1e-5f
#define PIECE 12544          // hid piece rows (4 pieces of 12544*512 bf16)

typedef unsigned int uint32;
typedef __attribute__((ext_vector_type(8))) short bf16x8;
typedef __attribute__((ext_vector_type(4))) float f32x4;
typedef __attribute__((ext_vector_type(16))) float f32x16;

__device__ __forceinline__ short f2bf(float x) {
  __hip_bfloat16 h = __float2bfloat16(x);
  return *reinterpret_cast<short*>(&h);
}
__device__ __forceinline__ float bflo(uint32 u) { return __uint_as_float(u << 16); }
__device__ __forceinline__ float bfhi(uint32 u) { return __uint_as_float(u & 0xffff0000u); }

// windowed token index -> source spatial token index
__device__ __forceinline__ int win_to_src(int grow) {
  int win = grow / NSEQ, n = grow % NSEQ;
  int b = win >> 6, gh = (win >> 3) & 7, gw = win & 7;
  int d = n / 49, rem = n % 49;
  int p = rem / 7, q = rem % 7;
  int h = p * 8 + gh, w = q * 8 + gw;
  return ((b * ND + d) * NHH + h) * NWW + w;
}

// ---------------- weights -> bf16 (concatenated: qkv|proj|fc1|fc2) -----------
__global__ void k_convw(const float* __restrict__ qkvw, const float* __restrict__ projw,
                        const float* __restrict__ fc1w, const float* __restrict__ fc2w,
                        short* __restrict__ out) {
  int i = blockIdx.x * 256 + threadIdx.x;   // 196608 total
  float v;
  if (i < 49152) v = qkvw[i];
  else if (i < 65536) v = projw[i - 49152];
  else if (i < 131072) v = fc1w[i - 65536];
  else v = fc2w[i - 131072];
  out[i] = f2bf(v);
}

// ---------------- LayerNorm1: one wave per row, shuffle reduce, bf16 out ------
__global__ __launch_bounds__(256) void k_ln1(const float* __restrict__ xin,
    const float* __restrict__ g, const float* __restrict__ bsh, short* __restrict__ out) {
  int w = threadIdx.x >> 6, lane = threadIdx.x & 63;
  float g0 = g[2 * lane], g1 = g[2 * lane + 1];
  float b0 = bsh[2 * lane], b1 = bsh[2 * lane + 1];
  for (int r = blockIdx.x * 4 + w; r < NTOK; r += gridDim.x * 4) {
    float2 v = *(const float2*)(xin + (long)r * NC + lane * 2);
    float s = v.x + v.y, s2 = v.x * v.x + v.y * v.y;
    #pragma unroll
    for (int m = 1; m < 64; m <<= 1) { s += __shfl_xor(s, m); s2 += __shfl_xor(s2, m); }
    float mu = s * (1.f / NC);
    float var = s2 * (1.f / NC) - mu * mu;
    float rr = rsqrtf(var + EPSV);
    uint32 p0 = (unsigned short)f2bf((v.x - mu) * rr * g0 + b0);
    uint32 p1 = (unsigned short)f2bf((v.y - mu) * rr * g1 + b1);
    *(uint32*)(out + (long)r * NC + lane * 2) = p0 | (p1 << 16);
  }
}

// ---------- depthwise 3x3 conv (SAME) + residual x: xsum = x + conv ----------
__global__ void k_dwconv(const short* __restrict__ xn, const float* __restrict__ xorig,
                         const float* __restrict__ wgt, const float* __restrict__ bias,
                         float* __restrict__ out) {
  int idx = blockIdx.x * 256 + threadIdx.x;       // over NTOK*64
  int cp = idx & 63;                               // channel pair
  int sp = idx >> 6;
  int w = sp % NWW;
  int h = (sp / NWW) % NHH;
  int bd = sp / (NWW * NHH);
  float a0 = bias[2 * cp], a1 = bias[2 * cp + 1];
  #pragma unroll
  for (int kh = 0; kh < 3; kh++) {
    int hh = h + kh - 1;
    if (hh < 0 || hh >= NHH) continue;
    #pragma unroll
    for (int kw = 0; kw < 3; kw++) {
      int ww = w + kw - 1;
      if (ww < 0 || ww >= NWW) continue;
      uint32 u = *(const uint32*)(xn + (((long)(bd * NHH + hh) * NWW + ww) << 7) + 2 * cp);
      a0 += bflo(u) * wgt[(kh * 3 + kw) * NC + 2 * cp];
      a1 += bfhi(u) * wgt[(kh * 3 + kw) * NC + 2 * cp + 1];
    }
  }
  float2 xo = *(const float2*)(xorig + ((long)sp << 7) + 2 * cp);
  *(float2*)(out + ((long)sp << 7) + 2 * cp) = make_float2(a0 + xo.x, a1 + xo.y);
}

// ---------------- MFMA GEMM: C[M,N] = A[M,K] * W[N,K]^T, 128x128 tile ---------
// MODE 0: qkv  — A gathered (windowed); out bf16 Q(scaled*log2e)/K/Vt
// MODE 1: proj — A=aout windowed; x1[src] = bf16(xsum[src] + bias + val) (scatter)
// MODE 2: fc1  — A=x1 bf16 with FUSED LayerNorm2; gelu -> hid pieces h0..h3
// MODE 3: fc2  — K=512, A-stage from hid pieces; d_out = x1 + bias + val (f32)
template <int NDIM, int KDIM, int MODE>
__global__ __launch_bounds__(256) void k_gemm_mfma(
    const short* __restrict__ A, const short* __restrict__ Wb,
    const float* __restrict__ bias, const float* __restrict__ gmm,
    const float* __restrict__ bta, const float* __restrict__ xsum,
    short* __restrict__ h0, short* __restrict__ h1,
    short* __restrict__ h2, short* __restrict__ h3,
    void* __restrict__ O0, void* __restrict__ O1, void* __restrict__ O2) {
  __shared__ char As[32768];
  __shared__ char Bs[32768];
  __shared__ int asrc[128];
  int tid = threadIdx.x;
  int m0 = blockIdx.x * 128;
  int n0 = blockIdx.y * 128;
  int lane = tid & 63, w = tid >> 6;
  int wm = w & 1, wn = w >> 1;
  int c16 = lane & 15, g = lane >> 4;

  if constexpr (MODE == 0 || MODE == 1) {
    if (tid < 128) asrc[tid] = win_to_src(m0 + tid);
  }
  if constexpr (MODE == 0) __syncthreads();

  float gv[8], bv[8];
  if constexpr (MODE == 2) {
    #pragma unroll
    for (int j = 0; j < 8; j++) {
      gv[j] = gmm[(tid & 15) * 8 + j];
      bv[j] = bta[(tid & 15) * 8 + j];
    }
  }
  const short* hpA = nullptr; int mloc0 = 0;
  if constexpr (MODE == 3) {
    int pc = m0 / PIECE;
    hpA = (pc == 0) ? h0 : (pc == 1) ? h1 : (pc == 2) ? h2 : h3;
    mloc0 = m0 - pc * PIECE;
  }

  f32x4 acc[4][4];
  #pragma unroll
  for (int i = 0; i < 4; i++)
    #pragma unroll
    for (int j = 0; j < 4; j++) acc[i][j] = f32x4{0.f, 0.f, 0.f, 0.f};

  const int KSTEPS = KDIM / 128;
  for (int ks = 0; ks < KSTEPS; ks++) {
    int k0 = ks * 128;
    if (ks > 0) __syncthreads();
    #pragma unroll
    for (int i = 0; i < 8; i++) {
      int idx = tid + i * 256;
      int row = idx >> 4, colq = idx & 15;
      int b = (row << 8) + (colq << 4); b ^= ((row & 7) << 4);
      if constexpr (MODE == 2) {
        // fused LayerNorm2 on x1 row (K=128, single step)
        uint4 va = *(const uint4*)(A + (long)(m0 + row) * 128 + colq * 8);
        unsigned short* us = (unsigned short*)&va;
        float f[8];
        float s = 0.f, s2 = 0.f;
        #pragma unroll
        for (int j = 0; j < 8; j++) {
          f[j] = bflo((uint32)us[j]);
          s += f[j]; s2 += f[j] * f[j];
        }
        #pragma unroll
        for (int mm = 1; mm < 16; mm <<= 1) { s += __shfl_xor(s, mm); s2 += __shfl_xor(s2, mm); }
        float mu = s * (1.f / NC);
        float var = s2 * (1.f / NC) - mu * mu;
        float rr = rsqrtf(var + EPSV);
        uint32 pk[4];
        #pragma unroll
        for (int j = 0; j < 4; j++) {
          uint32 lo = (unsigned short)f2bf((f[2 * j] - mu) * rr * gv[2 * j] + bv[2 * j]);
          uint32 hi = (unsigned short)f2bf((f[2 * j + 1] - mu) * rr * gv[2 * j + 1] + bv[2 * j + 1]);
          pk[j] = lo | (hi << 16);
        }
        *(uint4*)(As + b) = make_uint4(pk[0], pk[1], pk[2], pk[3]);
      } else {
        long arow;
        if constexpr (MODE == 0) arow = asrc[row];
        else if constexpr (MODE == 3) arow = mloc0 + row;
        else arow = m0 + row;
        const short* Ap = (MODE == 3) ? hpA : A;
        uint4 va = *(const uint4*)(Ap + arow * KDIM + k0 + colq * 8);
        *(uint4*)(As + b) = va;
      }
      uint4 vb = *(const uint4*)(Wb + (long)(n0 + row) * KDIM + k0 + colq * 8);
      *(uint4*)(Bs + b) = vb;
    }
    __syncthreads();
    #pragma unroll
    for (int kk = 0; kk < 4; kk++) {
      bf16x8 af[4], bfr[4];
      #pragma unroll
      for (int i = 0; i < 4; i++) {
        int ra = wm * 64 + i * 16 + c16;
        int ba = (ra << 8) + ((g + kk * 4) << 4); ba ^= ((ra & 7) << 4);
        af[i] = *(const bf16x8*)(As + ba);
        int rb = wn * 64 + i * 16 + c16;
        int bb = (rb << 8) + ((g + kk * 4) << 4); bb ^= ((rb & 7) << 4);
        bfr[i] = *(const bf16x8*)(Bs + bb);
      }
      #pragma unroll
      for (int i = 0; i < 4; i++)
        #pragma unroll
        for (int j = 0; j < 4; j++)
          acc[i][j] = __builtin_amdgcn_mfma_f32_16x16x32_bf16(af[i], bfr[j], acc[i][j], 0, 0, 0);
    }
  }

  short* hpO = nullptr; int pco = 0;
  if constexpr (MODE == 2) {
    pco = m0 / PIECE;
    hpO = (pco == 0) ? h0 : (pco == 1) ? h1 : (pco == 2) ? h2 : h3;
  }
  #pragma unroll
  for (int i = 0; i < 4; i++) {
    int gmb = m0 + wm * 64 + i * 16 + g * 4;
    #pragma unroll
    for (int j = 0; j < 4; j++) {
      int n = n0 + wn * 64 + j * 16 + c16;
      float bj = bias[n];
      #pragma unroll
      for (int r = 0; r < 4; r++) {
        int m = gmb + r;
        float v = acc[i][j][r] + bj;
        if constexpr (MODE == 0) {
          int which = n >> 7;                 // 0=q 1=k 2=v
          int head = (n & 127) >> 5, dim = n & 31;
          int win = m / NSEQ, tok = m % NSEQ;
          if (which == 0) {                   // scale/sqrt(d) * log2(e)
            long oidx = ((long)(win * NHEAD + head) * NSEQ + tok) * DHEAD + dim;
            ((short*)O0)[oidx] = f2bf(v * 0.2550348658f);
          } else if (which == 1) {
            long oidx = ((long)(win * NHEAD + head) * NSEQ + tok) * DHEAD + dim;
            ((short*)O1)[oidx] = f2bf(v);
          } else {                            // V transposed: [wh][d][n]
            long oidx = ((long)(win * NHEAD + head) * DHEAD + dim) * NSEQ + tok;
            ((short*)O2)[oidx] = f2bf(v);
          }
        } else if constexpr (MODE == 1) {
          long off = ((long)asrc[m - m0] << 7) + n;
          ((short*)O0)[off] = f2bf(xsum[off] + v);
        } else if constexpr (MODE == 2) {
          float gl = 0.5f * v * (1.0f + erff(v * 0.70710678118654752440f));
          hpO[((long)(m - pco * PIECE) << 9) + n] = f2bf(gl);
        } else {
          float xv = bflo((uint32)*(const unsigned short*)(A + ((long)m << 7) + n));
          ((float*)O0)[((long)m << 7) + n] = xv + v;
        }
      }
    }
  }
}

// ---------------- swapped-operand 32x32 MFMA attention, 8 waves ---------------
__global__ __launch_bounds__(512) void k_attn_mfma(
    const short* __restrict__ Q,   // [wh][n][32], pre-scaled by 1/sqrt(d)*log2e
    const short* __restrict__ Kk,  // [wh][n][32]
    const short* __restrict__ Vt,  // [wh][32][n]
    short* __restrict__ aout) {    // [win*392+q][128] bf16
  int wh = blockIdx.x, win = wh >> 2, head = wh & 3;
  __shared__ short Ks[NSEQ * 32];        // XOR-swizzled rows, 64 B stride
  __shared__ short Vs[32 * 408];         // stride 408; cols 392..407 zero
  int tid = threadIdx.x;
  int lane = tid & 63, w = tid >> 6;
  int ql = lane & 31, h = lane >> 5;

  const uint4* Kg4 = (const uint4*)(Kk + (long)wh * NSEQ * DHEAD);
  for (int i = tid; i < 1568; i += 512) {
    int b = i * 16; b ^= ((b >> 6) & 7) << 4;
    *(uint4*)((char*)Ks + b) = Kg4[i];
  }
  const uint2* Vg2 = (const uint2*)(Vt + (long)wh * DHEAD * NSEQ);
  for (int i = tid; i < 3136; i += 512) {
    int r = i / 98, cq = i - r * 98;
    *(uint2*)&Vs[r * 408 + cq * 4] = Vg2[i];
  }
  if (tid < 128) {
    int r = tid >> 2, cq = tid & 3;
    *(uint2*)&Vs[r * 408 + 392 + cq * 4] = make_uint2(0, 0);
  }
  __syncthreads();

  for (int t = w; t < 13; t += 8) {      // 32-row q tiles; tile 12 has 8 valid
    int q0 = t * 32;
    int qrow = q0 + ql; if (qrow > NSEQ - 1) qrow = NSEQ - 1;
    const short* Qr = Q + ((long)wh * NSEQ + qrow) * DHEAD;
    bf16x8 qf0 = *(const bf16x8*)(Qr + h * 8);
    bf16x8 qf1 = *(const bf16x8*)(Qr + 16 + h * 8);
    f32x16 o;
    #pragma unroll
    for (int r = 0; r < 16; r++) o[r] = 0.f;
    float mrun = -1e30f, lrun = 0.f;

    for (int c = 0; c < 13; c++) {
      int kb = c * 32;
      int krow = kb + ql;
      int sw = (krow & 7) << 4;
      int b0 = krow * 64 + h * 16;
      bf16x8 kf0 = *(const bf16x8*)((char*)Ks + (b0 ^ sw));
      bf16x8 kf1 = *(const bf16x8*)((char*)Ks + ((b0 + 32) ^ sw));
      f32x16 st;
      #pragma unroll
      for (int r = 0; r < 16; r++) st[r] = 0.f;
      __builtin_amdgcn_s_setprio(1);
      st = __builtin_amdgcn_mfma_f32_32x32x16_bf16(kf0, qf0, st, 0, 0, 0);
      st = __builtin_amdgcn_mfma_f32_32x32x16_bf16(kf1, qf1, st, 0, 0, 0);
      __builtin_amdgcn_s_setprio(0);
      if (c == 12) {
        #pragma unroll
        for (int r = 4; r < 16; r++) st[r] = -1e30f;
      }
      // ---- online softmax in exp2 domain, defer-max (THR=8 -> P<=256) ----
      float pmax = st[0];
      #pragma unroll
      for (int r = 1; r < 16; r++) pmax = fmaxf(pmax, st[r]);
      pmax = fmaxf(pmax, __shfl_xor(pmax, 32));
      if (!__all(pmax <= mrun + 8.f)) {
        float nm = fmaxf(mrun, pmax);
        float corr = exp2f(mrun - nm);
        mrun = nm;
        lrun *= corr;
        #pragma unroll
        for (int r = 0; r < 16; r++) o[r] *= corr;
      }
      float psum = 0.f;
      #pragma unroll
      for (int r = 0; r < 16; r++) { st[r] = exp2f(st[r] - mrun); psum += st[r]; }
      psum += __shfl_xor(psum, 32);
      lrun += psum;
      // ---- P^T frags via cvt_pk + permlane32_swap; PV ----
      #pragma unroll
      for (int s = 0; s < 2; s++) {
        if (s == 1 && c == 12) break;
        uint32 z0, z1, z2, z3;
        float p0 = st[8 * s + 0], p1 = st[8 * s + 1], p2 = st[8 * s + 2], p3 = st[8 * s + 3];
        float p4 = st[8 * s + 4], p5 = st[8 * s + 5], p6 = st[8 * s + 6], p7 = st[8 * s + 7];
        asm("v_cvt_pk_bf16_f32 %0, %1, %2" : "=v"(z0) : "v"(p0), "v"(p1));
        asm("v_cvt_pk_bf16_f32 %0, %1, %2" : "=v"(z1) : "v"(p2), "v"(p3));
        asm("v_cvt_pk_bf16_f32 %0, %1, %2" : "=v"(z2) : "v"(p4), "v"(p5));
        asm("v_cvt_pk_bf16_f32 %0, %1, %2" : "=v"(z3) : "v"(p6), "v"(p7));
        asm("v_permlane32_swap_b32 %0, %1" : "+v"(z0), "+v"(z2));
        asm("v_permlane32_swap_b32 %0, %1" : "+v"(z1), "+v"(z3));
        union { uint32 u[4]; bf16x8 v; } pb;
        pb.u[0] = z0; pb.u[1] = z1; pb.u[2] = z2; pb.u[3] = z3;
        bf16x8 vf = *(const bf16x8*)&Vs[ql * 408 + kb + 16 * s + 8 * h];
        __builtin_amdgcn_s_setprio(1);
        o = __builtin_amdgcn_mfma_f32_32x32x16_bf16(vf, pb.v, o, 0, 0, 0);
        __builtin_amdgcn_s_setprio(0);
      }
    }
    if (q0 + ql < NSEQ) {
      float inv = 1.0f / lrun;
      long base = ((long)win * NSEQ + q0 + ql) * NC + head * DHEAD;
      #pragma unroll
      for (int rr = 0; rr < 8; rr++) {
        int r = 2 * rr;
        int d = (r & 3) + 8 * (r >> 2) + 4 * h;
        float a0 = o[r] * inv, a1 = o[r + 1] * inv;
        uint32 pk;
        asm("v_cvt_pk_bf16_f32 %0, %1, %2" : "=v"(pk) : "v"(a0), "v"(a1));
        *(uint32*)(aout + base + d) = pk;
      }
    }
  }
}

extern "C" void kernel_launch(void* const* d_in, const int* in_sizes, int n_in,
                              void* d_out, int out_size, void* d_ws, size_t ws_size,
                              hipStream_t stream) {
  const float* x    = (const float*)d_in[0];
  const float* n1g  = (const float*)d_in[1];
  const float* n1b  = (const float*)d_in[2];
  const float* qkvw = (const float*)d_in[3];
  const float* qkvb = (const float*)d_in[4];
  const float* projw= (const float*)d_in[5];
  const float* projb= (const float*)d_in[6];
  const float* dww  = (const float*)d_in[7];
  const float* dwb  = (const float*)d_in[8];
  const float* n2g  = (const float*)d_in[9];
  const float* n2b  = (const float*)d_in[10];
  const float* fc1w = (const float*)d_in[11];
  const float* fc1b = (const float*)d_in[12];
  const float* fc2w = (const float*)d_in[13];
  const float* fc2b = (const float*)d_in[14];

  char* ws = (char*)d_ws;
  // layout (bytes), total 77,463,552 < 89.9MB proven:
  short* wb_q = (short*)(ws + 0);              // 49152 sh
  short* wb_p = wb_q + 49152;
  short* wb_1 = wb_p + 16384;
  short* wb_2 = wb_1 + 65536;                  // end 393216 B
  short* xnb  = (short*)(ws + 393216);         // 12.8MB bf16 [-> aout -> hid p0]
  float* xsum = (float*)(ws + 13238272);       // 25.7MB f32  [-> hid p1,p2]
  short* Qb   = (short*)(ws + 38928384);       // 12.8MB      [-> x1]
  short* Kb   = (short*)(ws + 51773440);       // 12.8MB      [-> hid p3]
  short* Vb   = (short*)(ws + 64618496);       // 12.8MB (end 77463552)
  short* aoutb = xnb;
  short* x1b   = Qb;
  short* hid0  = xnb;
  short* hid1  = (short*)(ws + 13238272);
  short* hid2  = (short*)(ws + 26083328);
  short* hid3  = Kb;

  k_convw<<<768, 256, 0, stream>>>(qkvw, projw, fc1w, fc2w, wb_q);
  k_ln1<<<1024, 256, 0, stream>>>(x, n1g, n1b, xnb);
  k_dwconv<<<(NTOK * 64) / 256, 256, 0, stream>>>(xnb, x, dww, dwb, xsum);
  k_gemm_mfma<384, 128, 0><<<dim3(392, 3), 256, 0, stream>>>(
      xnb, wb_q, qkvb, nullptr, nullptr, nullptr,
      nullptr, nullptr, nullptr, nullptr, Qb, Kb, Vb);
  k_attn_mfma<<<NWIN * NHEAD, 512, 0, stream>>>(Qb, Kb, Vb, aoutb);
  k_gemm_mfma<128, 128, 1><<<dim3(392, 1), 256, 0, stream>>>(
      aoutb, wb_p, projb, nullptr, nullptr, xsum,
      nullptr, nullptr, nullptr, nullptr, x1b, nullptr, nullptr);
  k_gemm_mfma<512, 128, 2><<<dim3(392, 4), 256, 0, stream>>>(
      x1b, wb_1, fc1b, n2g, n2b, nullptr,
      hid0, hid1, hid2, hid3, nullptr, nullptr, nullptr);
  k_gemm_mfma<128, 512, 3><<<dim3(392, 1), 256, 0, stream>>>(
      x1b, wb_2, fc2b, nullptr, nullptr, nullptr,
      hid0, hid1, hid2, hid3, d_out, nullptr, nullptr);
}